// Round 2
// baseline (12358.912 us; speedup 1.0000x reference)
//
#include <hip/hip_runtime.h>
#include <math.h>

#define NN   16384      // total nodes
#define NE   262144     // edges (no self loops)
#define NB   64         // graphs
#define SEQT 256        // nodes per graph (= seq len)
#define DEP  64
#define DOUT 256        // = HID
#define G3   768        // 3*HID

// ---------------------------------------------------------------------------
// degree / CSR build
// ---------------------------------------------------------------------------
__global__ void k_init_deg(int* deg) {
    int i = blockIdx.x * 256 + threadIdx.x;
    if (i < NN) deg[i] = 1;                       // self loop
}

__global__ void k_count(const int* __restrict__ ei, int* deg) {
    int e = blockIdx.x * 256 + threadIdx.x;
    if (e < NE) atomicAdd(&deg[ei[NE + e]], 1);   // col = dst
}

__global__ __launch_bounds__(1024) void k_scan_offs(const int* __restrict__ deg,
                                                    int* __restrict__ offs,
                                                    float* __restrict__ dinv) {
    __shared__ int lds[1024];
    const int tid = threadIdx.x;
    const int v0 = tid * 16;
    int loc[16];
    int s = 0;
#pragma unroll
    for (int i = 0; i < 16; ++i) {
        int d = deg[v0 + i];
        loc[i] = s;
        s += d - 1;                               // real in-edges only
        dinv[v0 + i] = rsqrtf((float)d);
    }
    lds[tid] = s;
    __syncthreads();
    for (int off = 1; off < 1024; off <<= 1) {
        int x = (tid >= off) ? lds[tid - off] : 0;
        __syncthreads();
        lds[tid] += x;
        __syncthreads();
    }
    int base = lds[tid] - s;                      // exclusive prefix of this thread
#pragma unroll
    for (int i = 0; i < 16; ++i) offs[v0 + i] = base + loc[i];
}

__global__ void k_fill(const int* __restrict__ ei, const int* __restrict__ offs,
                       int* cursor, int* __restrict__ eidx) {
    int e = blockIdx.x * 256 + threadIdx.x;
    if (e < NE) {
        int c = ei[NE + e];
        int pos = offs[c] + atomicAdd(&cursor[c], 1);
        eidx[pos] = e;
    }
}

__global__ void k_bself(const float* __restrict__ WB, float* Bself) {
    int f = threadIdx.x;                          // 256 threads
    float s = 0.f;
#pragma unroll
    for (int d = 0; d < DEP; ++d) s += WB[f * DEP + d];
    Bself[f] = s;
}

// ---------------------------------------------------------------------------
// generic fp32 GEMM:  C[M,N] = A[M,256] @ W[N,256]^T (+ bias[N])
// 128x128 tile, 8x8 micro, BK=8, 256 threads
// ---------------------------------------------------------------------------
__global__ __launch_bounds__(256) void k_gemm(const float* __restrict__ A,
                                              const float* __restrict__ W,
                                              const float* __restrict__ bias,
                                              float* __restrict__ C,
                                              int M, int N) {
    __shared__ float As[8][132];
    __shared__ float Ws[8][132];
    const int tid = threadIdx.x;
    const int m0 = blockIdx.x * 128;
    const int n0 = blockIdx.y * 128;
    const int lr = tid >> 1;                      // 0..127
    const int lk = (tid & 1) * 4;                 // 0 or 4
    const int tm = tid & 15, tn = tid >> 4;

    float acc[8][8];
#pragma unroll
    for (int i = 0; i < 8; ++i)
#pragma unroll
        for (int j = 0; j < 8; ++j) acc[i][j] = 0.f;

    for (int k0 = 0; k0 < 256; k0 += 8) {
        float4 av = *(const float4*)&A[(size_t)(m0 + lr) * 256 + k0 + lk];
        float4 wv = *(const float4*)&W[(size_t)(n0 + lr) * 256 + k0 + lk];
        As[lk + 0][lr] = av.x; As[lk + 1][lr] = av.y;
        As[lk + 2][lr] = av.z; As[lk + 3][lr] = av.w;
        Ws[lk + 0][lr] = wv.x; Ws[lk + 1][lr] = wv.y;
        Ws[lk + 2][lr] = wv.z; Ws[lk + 3][lr] = wv.w;
        __syncthreads();
#pragma unroll
        for (int kk = 0; kk < 8; ++kk) {
            float a[8], b[8];
            *(float4*)&a[0] = *(const float4*)&As[kk][tm * 8];
            *(float4*)&a[4] = *(const float4*)&As[kk][tm * 8 + 4];
            *(float4*)&b[0] = *(const float4*)&Ws[kk][tn * 8];
            *(float4*)&b[4] = *(const float4*)&Ws[kk][tn * 8 + 4];
#pragma unroll
            for (int i = 0; i < 8; ++i)
#pragma unroll
                for (int j = 0; j < 8; ++j)
                    acc[i][j] = fmaf(a[i], b[j], acc[i][j]);
        }
        __syncthreads();
    }

    float bv[8];
#pragma unroll
    for (int j = 0; j < 8; ++j) bv[j] = bias ? bias[n0 + tn * 8 + j] : 0.f;
#pragma unroll
    for (int i = 0; i < 8; ++i) {
        int m = m0 + tm * 8 + i;
        float4 o0, o1;
        o0.x = acc[i][0] + bv[0]; o0.y = acc[i][1] + bv[1];
        o0.z = acc[i][2] + bv[2]; o0.w = acc[i][3] + bv[3];
        o1.x = acc[i][4] + bv[4]; o1.y = acc[i][5] + bv[5];
        o1.z = acc[i][6] + bv[6]; o1.w = acc[i][7] + bv[7];
        *(float4*)&C[(size_t)m * N + n0 + tn * 8]     = o0;
        *(float4*)&C[(size_t)m * N + n0 + tn * 8 + 4] = o1;
    }
}

// ---------------------------------------------------------------------------
// GCN gather: one WG (256 thr) per node.  WB row in registers (fused Be).
// ---------------------------------------------------------------------------
__global__ __launch_bounds__(256) void k_gcn(const float* __restrict__ Ax,
                                             const float* __restrict__ WB,
                                             const float* __restrict__ edge_attr,
                                             const int* __restrict__ ei,
                                             const int* __restrict__ eidx,
                                             const int* __restrict__ offs,
                                             const int* __restrict__ deg,
                                             const float* __restrict__ dinv,
                                             const float* __restrict__ Bself,
                                             const float* __restrict__ gcn_bias,
                                             float* __restrict__ node) {
    const int v = blockIdx.x;
    const int f = threadIdx.x;

    float wb[64];
#pragma unroll
    for (int d4 = 0; d4 < 16; ++d4) {
        float4 t = *(const float4*)&WB[f * DEP + d4 * 4];
        wb[d4 * 4 + 0] = t.x; wb[d4 * 4 + 1] = t.y;
        wb[d4 * 4 + 2] = t.z; wb[d4 * 4 + 3] = t.w;
    }

    __shared__ float ea[2][64];
    __shared__ int   src_s[2];
    const int base = offs[v];
    const int cnt  = deg[v] - 1;
    const float dv = dinv[v];
    float acc = 0.f;

    if (cnt > 0) {
        if (f < 64) {
            int e0 = eidx[base];
            ea[0][f] = edge_attr[(size_t)e0 * DEP + f];
            if (f == 0) src_s[0] = ei[e0];
        }
        __syncthreads();
        for (int i = 0; i < cnt; ++i) {
            int cur = i & 1;
            if (i + 1 < cnt && f < 64) {
                int e1 = eidx[base + i + 1];
                ea[cur ^ 1][f] = edge_attr[(size_t)e1 * DEP + f];
                if (f == 0) src_s[cur ^ 1] = ei[e1];
            }
            int s = src_s[cur];
            float be = 0.f;
#pragma unroll
            for (int d = 0; d < 64; ++d) be = fmaf(wb[d], ea[cur][d], be);
            float ax = Ax[(size_t)s * DOUT + f];
            acc = fmaf(dinv[s] * dv, tanhf(ax * be), acc);
            __syncthreads();
        }
    }
    // self loop: norm = dinv[v]^2, Be = rowsum(WB)
    acc += dv * dv * tanhf(Ax[(size_t)v * DOUT + f] * Bself[f]);
    node[(size_t)v * DOUT + f] = tanhf(acc / (float)(cnt + 1) + gcn_bias[f]);
}

// ---------------------------------------------------------------------------
// GRU scan v2: ONE workgroup (1024 thr) per graph — all sync is __syncthreads.
// w_hh fully register-resident: thread (q=tid>>3, c=tid&7) holds rows
// [6q,6q+6) x cols [32c,32c+32) = 192 floats.  h in LDS, XOR-swizzled in
// 16B chunks so the 8 ds_read_b128 per thread are bank-conflict-free.
// ---------------------------------------------------------------------------
__device__ __forceinline__ int h_phys(int k) {
    // logical float index k in [0,256) -> physical float index (16B swizzle)
    int c = k >> 5, j = (k >> 2) & 7, o = k & 3;
    return ((c << 3) | ((j + c) & 7)) * 4 + o;
}

__global__ __launch_bounds__(1024) void k_gru_scan(const float* __restrict__ xp,
                                                   const float* __restrict__ w_hh,
                                                   const float* __restrict__ b_hh,
                                                   float* __restrict__ y,
                                                   float* __restrict__ hT) {
    const int tid = threadIdx.x;
    const int b   = blockIdx.x;                  // graph
    const int c   = tid & 7;                     // col block: cols [32c, 32c+32)
    const int q   = tid >> 3;                    // row block: rows [6q, 6q+6)

    // --- weight slice -> registers (192 floats, all-constant indices) ---
    float w[6][32];
    {
        const float* wp = w_hh + (size_t)(q * 6) * 256 + c * 32;
#pragma unroll
        for (int i = 0; i < 6; ++i) {
#pragma unroll
            for (int k4 = 0; k4 < 8; ++k4) {
                float4 t = *(const float4*)&wp[i * 256 + k4 * 4];
                w[i][k4 * 4 + 0] = t.x; w[i][k4 * 4 + 1] = t.y;
                w[i][k4 * 4 + 2] = t.z; w[i][k4 * 4 + 3] = t.w;
            }
        }
    }
    float bhr = 0.f, bhz = 0.f, bhn = 0.f;
    int   pj  = 0;
    if (tid < 256) {
        bhr = b_hh[tid]; bhz = b_hh[256 + tid]; bhn = b_hh[512 + tid];
        pj  = h_phys(tid);
    }

    __shared__ float hL[256];                    // swizzled h(t)
    __shared__ float ghL[768];                   // w_hh @ h
    if (tid < 256) hL[tid] = 0.f;                // h(0) = 0 (any perm of zeros)
    __syncthreads();

    const float* xpb = xp + (size_t)b * SEQT * G3;
    float*       yb  = y  + (size_t)b * SEQT * DOUT;

    for (int t = 0; t < SEQT; ++t) {
        // prefetch this step's xp early (vmcnt-wait lands after the FMA block)
        float xr = 0.f, xz = 0.f, xn = 0.f;
        if (tid < 256) {
            const float* xpt = xpb + (size_t)t * G3 + tid;
            xr = xpt[0]; xz = xpt[256]; xn = xpt[512];
        }

        // h(t) -> registers (8 x ds_read_b128, swizzle => conflict-free)
        float hreg[32];
#pragma unroll
        for (int j = 0; j < 8; ++j) {
            const float4 hv = *(const float4*)&hL[((c << 3) | ((j + c) & 7)) * 4];
            hreg[j * 4 + 0] = hv.x; hreg[j * 4 + 1] = hv.y;
            hreg[j * 4 + 2] = hv.z; hreg[j * 4 + 3] = hv.w;
        }

        // partial dots: 6 rows x 32 cols
        float acc[6];
#pragma unroll
        for (int i = 0; i < 6; ++i) {
            float s = 0.f;
#pragma unroll
            for (int k = 0; k < 32; ++k) s = fmaf(w[i][k], hreg[k], s);
            acc[i] = s;
        }
        // butterfly over the 8 col-blocks (lane bits 0..2)
#pragma unroll
        for (int m = 1; m < 8; m <<= 1) {
#pragma unroll
            for (int i = 0; i < 6; ++i) acc[i] += __shfl_xor(acc[i], m, 64);
        }
        if (c == 0) {
#pragma unroll
            for (int i = 0; i < 6; ++i) ghL[q * 6 + i] = acc[i];
        }
        __syncthreads();                          // gh ready; hreg consumed

        if (tid < 256) {
            const int j = tid;
            float ghr = ghL[j]       + bhr;
            float ghz = ghL[256 + j] + bhz;
            float ghn = ghL[512 + j] + bhn;
            float h_old = hL[pj];
            float r = 1.f / (1.f + __expf(-(xr + ghr)));
            float z = 1.f / (1.f + __expf(-(xz + ghz)));
            float n = tanhf(xn + r * ghn);
            float hn = (1.f - z) * n + z * h_old;
            hL[pj] = hn;
            yb[(size_t)t * DOUT + j] = hn;
            if (t == SEQT - 1) hT[b * 256 + j] = hn;
        }
        __syncthreads();                          // h(t+1) visible to all
    }
}

// ---------------------------------------------------------------------------
// pooling + linear + softmax: one WG per graph
// ---------------------------------------------------------------------------
__global__ __launch_bounds__(256) void k_final(const float* __restrict__ y2,
                                               const float* __restrict__ hT,
                                               const float* __restrict__ lin_W,
                                               const float* __restrict__ lin_b,
                                               float* __restrict__ out) {
    __shared__ float pool[1280];
    __shared__ float red[2][256];
    const int b = blockIdx.x, j = threadIdx.x;
    float mx = -1e30f, sm = 0.f;
    for (int t = 0; t < SEQT; ++t) {
        float v = y2[((size_t)(b * SEQT + t)) * DOUT + j];
        mx = fmaxf(mx, v);
        sm += v;
    }
    pool[j]        = hT[b * 256 + j];
    pool[256 + j]  = hT[16384 + b * 256 + j];
    pool[512 + j]  = hT[32768 + b * 256 + j];
    pool[768 + j]  = mx;
    pool[1024 + j] = sm * (1.f / 256.f);
    __syncthreads();
    float p0 = 0.f, p1 = 0.f;
    for (int i = j; i < 1280; i += 256) {
        float pv = pool[i];
        p0 = fmaf(lin_W[i], pv, p0);
        p1 = fmaf(lin_W[1280 + i], pv, p1);
    }
    red[0][j] = p0; red[1][j] = p1;
    __syncthreads();
    if (j == 0) {
        float l0 = lin_b[0], l1 = lin_b[1];
        for (int i = 0; i < 256; ++i) { l0 += red[0][i]; l1 += red[1][i]; }
        float m = fmaxf(l0, l1);
        float e0 = __expf(l0 - m), e1 = __expf(l1 - m);
        float s = e0 + e1;
        out[b * 2 + 0] = e0 / s;
        out[b * 2 + 1] = e1 / s;
    }
}

// ---------------------------------------------------------------------------
extern "C" void kernel_launch(void* const* d_in, const int* in_sizes, int n_in,
                              void* d_out, int out_size, void* d_ws, size_t ws_size,
                              hipStream_t stream) {
    const float* x         = (const float*)d_in[0];
    const float* edge_attr = (const float*)d_in[1];
    const int*   ei        = (const int*)d_in[2];
    const float* WA        = (const float*)d_in[3];
    const float* WB        = (const float*)d_in[4];
    const float* gcn_bias  = (const float*)d_in[5];
    const float* w_ih[3] = {(const float*)d_in[6],  (const float*)d_in[10], (const float*)d_in[14]};
    const float* w_hh[3] = {(const float*)d_in[7],  (const float*)d_in[11], (const float*)d_in[15]};
    const float* b_ih[3] = {(const float*)d_in[8],  (const float*)d_in[12], (const float*)d_in[16]};
    const float* b_hh[3] = {(const float*)d_in[9],  (const float*)d_in[13], (const float*)d_in[17]};
    const float* lin_W = (const float*)d_in[18];
    const float* lin_b = (const float*)d_in[19];
    float* out = (float*)d_out;

    char* p = (char*)d_ws;
    auto alloc = [&](size_t bytes) {
        char* r = p;
        p += (bytes + 255) & ~(size_t)255;
        return r;
    };
    int*   deg    = (int*)alloc((size_t)NN * 4);
    int*   offs   = (int*)alloc((size_t)NN * 4);
    int*   cursor = (int*)alloc((size_t)NN * 4);
    float* dinv   = (float*)alloc((size_t)NN * 4);
    int*   eidx   = (int*)alloc((size_t)NE * 4);
    float* Bself  = (float*)alloc(256 * 4);
    float* hT     = (float*)alloc(3 * NB * 256 * 4);
    float* node   = (float*)alloc((size_t)NN * DOUT * 4);
    float* yA     = (float*)alloc((size_t)NN * DOUT * 4);
    float* yB     = (float*)alloc((size_t)NN * DOUT * 4);
    float* xp     = (float*)alloc((size_t)NN * G3 * 4);
    float* Ax     = xp;   // alias: Ax dead before xp is first written

    // --- GCN ---
    hipMemsetAsync(cursor, 0, (size_t)NN * 4, stream);
    k_init_deg<<<NN / 256, 256, 0, stream>>>(deg);
    k_count<<<NE / 256, 256, 0, stream>>>(ei, deg);
    k_scan_offs<<<1, 1024, 0, stream>>>(deg, offs, dinv);
    k_fill<<<NE / 256, 256, 0, stream>>>(ei, offs, cursor, eidx);
    k_bself<<<1, 256, 0, stream>>>(WB, Bself);
    {
        dim3 g(NN / 128, 256 / 128);
        k_gemm<<<g, 256, 0, stream>>>(x, WA, nullptr, Ax, NN, 256);
    }
    k_gcn<<<NN, 256, 0, stream>>>(Ax, WB, edge_attr, ei, eidx, offs, deg, dinv,
                                  Bself, gcn_bias, node);

    // --- GRU x3 ---
    const float* in_seq = node;
    float* y_outs[3] = {yA, yB, yA};
    for (int l = 0; l < 3; ++l) {
        dim3 g(NN / 128, G3 / 128);
        k_gemm<<<g, 256, 0, stream>>>(in_seq, w_ih[l], b_ih[l], xp, NN, G3);
        k_gru_scan<<<NB, 1024, 0, stream>>>(xp, w_hh[l], b_hh[l], y_outs[l],
                                            hT + l * NB * 256);
        in_seq = y_outs[l];
    }

    // --- pool + linear + softmax ---
    k_final<<<NB, 256, 0, stream>>>(yA, hT, lin_W, lin_b, out);
}

// Round 4
// 2617.575 us; speedup vs baseline: 4.7215x; 4.7215x over previous
//
#include <hip/hip_runtime.h>
#include <math.h>

#define NN   16384      // total nodes
#define NE   262144     // edges (no self loops)
#define NB   64         // graphs
#define SEQT 256        // nodes per graph (= seq len)
#define DEP  64
#define DOUT 256        // = HID
#define G3   768        // 3*HID

typedef _Float16 h2_t __attribute__((ext_vector_type(2)));

// cvt_pkrtz returns __fp16x2; same-size vector C-cast is a bitcast
static __device__ __forceinline__ h2_t pk(float a, float b) {
    return (h2_t)__builtin_amdgcn_cvt_pkrtz(a, b);
}

static __device__ __forceinline__ float dot2(h2_t a, h2_t b, float c) {
#if __has_builtin(__builtin_amdgcn_fdot2)
    return __builtin_amdgcn_fdot2(a, b, c, false);
#else
    return fmaf((float)a.x, (float)b.x, fmaf((float)a.y, (float)b.y, c));
#endif
}

// ---------------------------------------------------------------------------
// degree / CSR build
// ---------------------------------------------------------------------------
__global__ void k_init_deg(int* deg) {
    int i = blockIdx.x * 256 + threadIdx.x;
    if (i < NN) deg[i] = 1;                       // self loop
}

__global__ void k_count(const int* __restrict__ ei, int* deg) {
    int e = blockIdx.x * 256 + threadIdx.x;
    if (e < NE) atomicAdd(&deg[ei[NE + e]], 1);   // col = dst
}

__global__ __launch_bounds__(1024) void k_scan_offs(const int* __restrict__ deg,
                                                    int* __restrict__ offs,
                                                    float* __restrict__ dinv) {
    __shared__ int lds[1024];
    const int tid = threadIdx.x;
    const int v0 = tid * 16;
    int loc[16];
    int s = 0;
#pragma unroll
    for (int i = 0; i < 16; ++i) {
        int d = deg[v0 + i];
        loc[i] = s;
        s += d - 1;                               // real in-edges only
        dinv[v0 + i] = rsqrtf((float)d);
    }
    lds[tid] = s;
    __syncthreads();
    for (int off = 1; off < 1024; off <<= 1) {
        int x = (tid >= off) ? lds[tid - off] : 0;
        __syncthreads();
        lds[tid] += x;
        __syncthreads();
    }
    int base = lds[tid] - s;                      // exclusive prefix of this thread
#pragma unroll
    for (int i = 0; i < 16; ++i) offs[v0 + i] = base + loc[i];
}

__global__ void k_fill(const int* __restrict__ ei, const int* __restrict__ offs,
                       int* cursor, int* __restrict__ eidx) {
    int e = blockIdx.x * 256 + threadIdx.x;
    if (e < NE) {
        int c = ei[NE + e];
        int pos = offs[c] + atomicAdd(&cursor[c], 1);
        eidx[pos] = e;
    }
}

__global__ void k_bself(const float* __restrict__ WB, float* Bself) {
    int f = threadIdx.x;                          // 256 threads
    float s = 0.f;
#pragma unroll
    for (int d = 0; d < DEP; ++d) s += WB[f * DEP + d];
    Bself[f] = s;
}

// ---------------------------------------------------------------------------
// generic fp32 GEMM:  C[M,N] = A[M,256] @ W[N,256]^T (+ bias[N])
// 128x128 tile, 8x8 micro, BK=8, 256 threads
// ---------------------------------------------------------------------------
__global__ __launch_bounds__(256) void k_gemm(const float* __restrict__ A,
                                              const float* __restrict__ W,
                                              const float* __restrict__ bias,
                                              float* __restrict__ C,
                                              int M, int N) {
    __shared__ float As[8][132];
    __shared__ float Ws[8][132];
    const int tid = threadIdx.x;
    const int m0 = blockIdx.x * 128;
    const int n0 = blockIdx.y * 128;
    const int lr = tid >> 1;                      // 0..127
    const int lk = (tid & 1) * 4;                 // 0 or 4
    const int tm = tid & 15, tn = tid >> 4;

    float acc[8][8];
#pragma unroll
    for (int i = 0; i < 8; ++i)
#pragma unroll
        for (int j = 0; j < 8; ++j) acc[i][j] = 0.f;

    for (int k0 = 0; k0 < 256; k0 += 8) {
        float4 av = *(const float4*)&A[(size_t)(m0 + lr) * 256 + k0 + lk];
        float4 wv = *(const float4*)&W[(size_t)(n0 + lr) * 256 + k0 + lk];
        As[lk + 0][lr] = av.x; As[lk + 1][lr] = av.y;
        As[lk + 2][lr] = av.z; As[lk + 3][lr] = av.w;
        Ws[lk + 0][lr] = wv.x; Ws[lk + 1][lr] = wv.y;
        Ws[lk + 2][lr] = wv.z; Ws[lk + 3][lr] = wv.w;
        __syncthreads();
#pragma unroll
        for (int kk = 0; kk < 8; ++kk) {
            float a[8], b[8];
            *(float4*)&a[0] = *(const float4*)&As[kk][tm * 8];
            *(float4*)&a[4] = *(const float4*)&As[kk][tm * 8 + 4];
            *(float4*)&b[0] = *(const float4*)&Ws[kk][tn * 8];
            *(float4*)&b[4] = *(const float4*)&Ws[kk][tn * 8 + 4];
#pragma unroll
            for (int i = 0; i < 8; ++i)
#pragma unroll
                for (int j = 0; j < 8; ++j)
                    acc[i][j] = fmaf(a[i], b[j], acc[i][j]);
        }
        __syncthreads();
    }

    float bv[8];
#pragma unroll
    for (int j = 0; j < 8; ++j) bv[j] = bias ? bias[n0 + tn * 8 + j] : 0.f;
#pragma unroll
    for (int i = 0; i < 8; ++i) {
        int m = m0 + tm * 8 + i;
        float4 o0, o1;
        o0.x = acc[i][0] + bv[0]; o0.y = acc[i][1] + bv[1];
        o0.z = acc[i][2] + bv[2]; o0.w = acc[i][3] + bv[3];
        o1.x = acc[i][4] + bv[4]; o1.y = acc[i][5] + bv[5];
        o1.z = acc[i][6] + bv[6]; o1.w = acc[i][7] + bv[7];
        *(float4*)&C[(size_t)m * N + n0 + tn * 8]     = o0;
        *(float4*)&C[(size_t)m * N + n0 + tn * 8 + 4] = o1;
    }
}

// ---------------------------------------------------------------------------
// GCN gather: one WG (256 thr) per node.  WB row in registers (fused Be).
// ---------------------------------------------------------------------------
__global__ __launch_bounds__(256) void k_gcn(const float* __restrict__ Ax,
                                             const float* __restrict__ WB,
                                             const float* __restrict__ edge_attr,
                                             const int* __restrict__ ei,
                                             const int* __restrict__ eidx,
                                             const int* __restrict__ offs,
                                             const int* __restrict__ deg,
                                             const float* __restrict__ dinv,
                                             const float* __restrict__ Bself,
                                             const float* __restrict__ gcn_bias,
                                             float* __restrict__ node) {
    const int v = blockIdx.x;
    const int f = threadIdx.x;

    float wb[64];
#pragma unroll
    for (int d4 = 0; d4 < 16; ++d4) {
        float4 t = *(const float4*)&WB[f * DEP + d4 * 4];
        wb[d4 * 4 + 0] = t.x; wb[d4 * 4 + 1] = t.y;
        wb[d4 * 4 + 2] = t.z; wb[d4 * 4 + 3] = t.w;
    }

    __shared__ float ea[2][64];
    __shared__ int   src_s[2];
    const int base = offs[v];
    const int cnt  = deg[v] - 1;
    const float dv = dinv[v];
    float acc = 0.f;

    if (cnt > 0) {
        if (f < 64) {
            int e0 = eidx[base];
            ea[0][f] = edge_attr[(size_t)e0 * DEP + f];
            if (f == 0) src_s[0] = ei[e0];
        }
        __syncthreads();
        for (int i = 0; i < cnt; ++i) {
            int cur = i & 1;
            if (i + 1 < cnt && f < 64) {
                int e1 = eidx[base + i + 1];
                ea[cur ^ 1][f] = edge_attr[(size_t)e1 * DEP + f];
                if (f == 0) src_s[cur ^ 1] = ei[e1];
            }
            int s = src_s[cur];
            float be = 0.f;
#pragma unroll
            for (int d = 0; d < 64; ++d) be = fmaf(wb[d], ea[cur][d], be);
            float ax = Ax[(size_t)s * DOUT + f];
            acc = fmaf(dinv[s] * dv, tanhf(ax * be), acc);
            __syncthreads();
        }
    }
    // self loop: norm = dinv[v]^2, Be = rowsum(WB)
    acc += dv * dv * tanhf(Ax[(size_t)v * DOUT + f] * Bself[f]);
    node[(size_t)v * DOUT + f] = tanhf(acc / (float)(cnt + 1) + gcn_bias[f]);
}

// ---------------------------------------------------------------------------
// GRU scan v3: ONE 512-thread WG per graph, w_hh register-resident as f16.
// Thread (q=tid>>3, c=tid&7) holds rows [12q,12q+12) x cols [32c,32c+32)
// = 384 f16 = 192 VGPRs (packed half2).  2 waves/SIMD -> 256-VGPR cap, no
// spill (round-2 failure mode: 1024-thr WG caps VGPR at 128 -> forced spill).
// h carried fp32 in LDS (exact state), packed to f16 only as dot input.
// v_dot2_f32_f16: 2 MAC/instr, fp32 accumulate.
// ---------------------------------------------------------------------------
__global__ __launch_bounds__(512, 2) void k_gru_scan(const float* __restrict__ xp,
                                                     const float* __restrict__ w_hh,
                                                     const float* __restrict__ b_hh,
                                                     float* __restrict__ y,
                                                     float* __restrict__ hT) {
    const int tid = threadIdx.x;
    const int b   = blockIdx.x;                  // graph
    const int c   = tid & 7;                     // col block: cols [32c, 32c+32)
    const int q   = tid >> 3;                    // row block: rows [12q, 12q+12)

    // --- weight slice -> registers as packed f16 (compile-time indices) ---
    h2_t w[12][16];
    {
        const float* wp = w_hh + (size_t)(q * 12) * 256 + c * 32;
#pragma unroll
        for (int i = 0; i < 12; ++i) {
#pragma unroll
            for (int k4 = 0; k4 < 8; ++k4) {
                float4 t = *(const float4*)&wp[i * 256 + k4 * 4];
                w[i][k4 * 2 + 0] = pk(t.x, t.y);
                w[i][k4 * 2 + 1] = pk(t.z, t.w);
            }
        }
    }
    float bhr = 0.f, bhz = 0.f, bhn = 0.f;
    if (tid < 256) {
        bhr = b_hh[tid]; bhz = b_hh[256 + tid]; bhn = b_hh[512 + tid];
    }

    __shared__ float hL[256];                    // h(t), fp32
    __shared__ float ghL[768];                   // w_hh @ h
    if (tid < 256) hL[tid] = 0.f;                // h(0) = 0
    __syncthreads();

    const float* xpb = xp + (size_t)b * SEQT * G3;
    float*       yb  = y  + (size_t)b * SEQT * DOUT;

    for (int t = 0; t < SEQT; ++t) {
        // prefetch this step's xp early (vmcnt-wait lands in the gate phase)
        float xr = 0.f, xz = 0.f, xn = 0.f;
        if (tid < 256) {
            const float* xpt = xpb + (size_t)t * G3 + tid;
            xr = xpt[0]; xz = xpt[256]; xn = xpt[512];
        }

        // h(t) -> packed f16 regs (8 x ds_read_b128; per wave: 8 distinct
        // bank-quads + same-address broadcast => conflict-free)
        h2_t h2[16];
#pragma unroll
        for (int j = 0; j < 8; ++j) {
            const float4 hv = *(const float4*)&hL[c * 32 + j * 4];
            h2[j * 2 + 0] = pk(hv.x, hv.y);
            h2[j * 2 + 1] = pk(hv.z, hv.w);
        }

        // partial dots: 12 rows x 32 cols (16 dot2 each), 12 independent chains
        float acc[12];
#pragma unroll
        for (int i = 0; i < 12; ++i) {
            float s = 0.f;
#pragma unroll
            for (int k = 0; k < 16; ++k) s = dot2(w[i][k], h2[k], s);
            acc[i] = s;
        }
        // butterfly over the 8 col-blocks (lane bits 0..2)
#pragma unroll
        for (int m = 1; m < 8; m <<= 1) {
#pragma unroll
            for (int i = 0; i < 12; ++i) acc[i] += __shfl_xor(acc[i], m, 64);
        }
        if (c == 0) {
#pragma unroll
            for (int i = 0; i < 12; ++i) ghL[q * 12 + i] = acc[i];
        }
        __syncthreads();                          // gh ready

        if (tid < 256) {
            const int j = tid;
            float ghr = ghL[j]       + bhr;
            float ghz = ghL[256 + j] + bhz;
            float ghn = ghL[512 + j] + bhn;
            float h_old = hL[j];
            float r = 1.f / (1.f + __expf(-(xr + ghr)));
            float z = 1.f / (1.f + __expf(-(xz + ghz)));
            float n = tanhf(xn + r * ghn);
            float hn = (1.f - z) * n + z * h_old;
            hL[j] = hn;
            yb[(size_t)t * DOUT + j] = hn;
            if (t == SEQT - 1) hT[b * 256 + j] = hn;
        }
        __syncthreads();                          // h(t+1) visible to all
    }
}

// ---------------------------------------------------------------------------
// pooling + linear + softmax: one WG per graph
// ---------------------------------------------------------------------------
__global__ __launch_bounds__(256) void k_final(const float* __restrict__ y2,
                                               const float* __restrict__ hT,
                                               const float* __restrict__ lin_W,
                                               const float* __restrict__ lin_b,
                                               float* __restrict__ out) {
    __shared__ float pool[1280];
    __shared__ float red[2][256];
    const int b = blockIdx.x, j = threadIdx.x;
    float mx = -1e30f, sm = 0.f;
    for (int t = 0; t < SEQT; ++t) {
        float v = y2[((size_t)(b * SEQT + t)) * DOUT + j];
        mx = fmaxf(mx, v);
        sm += v;
    }
    pool[j]        = hT[b * 256 + j];
    pool[256 + j]  = hT[16384 + b * 256 + j];
    pool[512 + j]  = hT[32768 + b * 256 + j];
    pool[768 + j]  = mx;
    pool[1024 + j] = sm * (1.f / 256.f);
    __syncthreads();
    float p0 = 0.f, p1 = 0.f;
    for (int i = j; i < 1280; i += 256) {
        float pv = pool[i];
        p0 = fmaf(lin_W[i], pv, p0);
        p1 = fmaf(lin_W[1280 + i], pv, p1);
    }
    red[0][j] = p0; red[1][j] = p1;
    __syncthreads();
    if (j == 0) {
        float l0 = lin_b[0], l1 = lin_b[1];
        for (int i = 0; i < 256; ++i) { l0 += red[0][i]; l1 += red[1][i]; }
        float m = fmaxf(l0, l1);
        float e0 = __expf(l0 - m), e1 = __expf(l1 - m);
        float s = e0 + e1;
        out[b * 2 + 0] = e0 / s;
        out[b * 2 + 1] = e1 / s;
    }
}

// ---------------------------------------------------------------------------
extern "C" void kernel_launch(void* const* d_in, const int* in_sizes, int n_in,
                              void* d_out, int out_size, void* d_ws, size_t ws_size,
                              hipStream_t stream) {
    const float* x         = (const float*)d_in[0];
    const float* edge_attr = (const float*)d_in[1];
    const int*   ei        = (const int*)d_in[2];
    const float* WA        = (const float*)d_in[3];
    const float* WB        = (const float*)d_in[4];
    const float* gcn_bias  = (const float*)d_in[5];
    const float* w_ih[3] = {(const float*)d_in[6],  (const float*)d_in[10], (const float*)d_in[14]};
    const float* w_hh[3] = {(const float*)d_in[7],  (const float*)d_in[11], (const float*)d_in[15]};
    const float* b_ih[3] = {(const float*)d_in[8],  (const float*)d_in[12], (const float*)d_in[16]};
    const float* b_hh[3] = {(const float*)d_in[9],  (const float*)d_in[13], (const float*)d_in[17]};
    const float* lin_W = (const float*)d_in[18];
    const float* lin_b = (const float*)d_in[19];
    float* out = (float*)d_out;

    char* p = (char*)d_ws;
    auto alloc = [&](size_t bytes) {
        char* r = p;
        p += (bytes + 255) & ~(size_t)255;
        return r;
    };
    int*   deg    = (int*)alloc((size_t)NN * 4);
    int*   offs   = (int*)alloc((size_t)NN * 4);
    int*   cursor = (int*)alloc((size_t)NN * 4);
    float* dinv   = (float*)alloc((size_t)NN * 4);
    int*   eidx   = (int*)alloc((size_t)NE * 4);
    float* Bself  = (float*)alloc(256 * 4);
    float* hT     = (float*)alloc(3 * NB * 256 * 4);
    float* node   = (float*)alloc((size_t)NN * DOUT * 4);
    float* yA     = (float*)alloc((size_t)NN * DOUT * 4);
    float* yB     = (float*)alloc((size_t)NN * DOUT * 4);
    float* xp     = (float*)alloc((size_t)NN * G3 * 4);
    float* Ax     = xp;   // alias: Ax dead before xp is first written

    // --- GCN ---
    hipMemsetAsync(cursor, 0, (size_t)NN * 4, stream);
    k_init_deg<<<NN / 256, 256, 0, stream>>>(deg);
    k_count<<<NE / 256, 256, 0, stream>>>(ei, deg);
    k_scan_offs<<<1, 1024, 0, stream>>>(deg, offs, dinv);
    k_fill<<<NE / 256, 256, 0, stream>>>(ei, offs, cursor, eidx);
    k_bself<<<1, 256, 0, stream>>>(WB, Bself);
    {
        dim3 g(NN / 128, 256 / 128);
        k_gemm<<<g, 256, 0, stream>>>(x, WA, nullptr, Ax, NN, 256);
    }
    k_gcn<<<NN, 256, 0, stream>>>(Ax, WB, edge_attr, ei, eidx, offs, deg, dinv,
                                  Bself, gcn_bias, node);

    // --- GRU x3 ---
    const float* in_seq = node;
    float* y_outs[3] = {yA, yB, yA};
    for (int l = 0; l < 3; ++l) {
        dim3 g(NN / 128, G3 / 128);
        k_gemm<<<g, 256, 0, stream>>>(in_seq, w_ih[l], b_ih[l], xp, NN, G3);
        k_gru_scan<<<NB, 512, 0, stream>>>(xp, w_hh[l], b_hh[l], y_outs[l],
                                           hT + l * NB * 256);
        in_seq = y_outs[l];
    }

    // --- pool + linear + softmax ---
    k_final<<<NB, 256, 0, stream>>>(yA, hT, lin_W, lin_b, out);
}